// Round 1
// baseline (34.025 us; speedup 1.0000x reference)
//
#include <hip/hip_runtime.h>

// ROI max-pool, matching the JAX reference exactly.
// feature_map: (1, 256, 50, 50) f32, bboxes: (512, 4) f32
// output: (512, 256, 7, 7) f32
// spatial_scale = 1/16, pooled = 7

#define CC   256
#define HH   50
#define WW   50
#define NBOX 512
#define PP   7
#define SCL  (1.0f / 16.0f)

__global__ __launch_bounds__(256) void ROIPool_kernel(
    const float* __restrict__ feat,
    const float* __restrict__ boxes,
    float* __restrict__ out,
    int total)
{
    int idx = blockIdx.x * blockDim.x + threadIdx.x;
    if (idx >= total) return;

    // idx = ((n*CC + c)*PP + p)*PP + q   (q fastest -> coalesced writes)
    int q = idx % PP;
    int t = idx / PP;
    int p = t % PP;
    t /= PP;
    int c = t & (CC - 1);
    int n = t >> 8;

    const float* b = boxes + n * 4;
    // r = floor(box * scale + 0.5) ; coords are non-negative so (int) == floor
    int x1 = (int)floorf(b[0] * SCL + 0.5f);
    int y1 = (int)floorf(b[1] * SCL + 0.5f);
    int x2 = (int)floorf(b[2] * SCL + 0.5f);
    int y2 = (int)floorf(b[3] * SCL + 0.5f);

    int rw = max(x2 - x1 + 1, 1);
    int rh = max(y2 - y1 + 1, 1);

    // Python floor-div on non-negative ints == C truncating div
    int hs = min(max(p * rh / PP + y1, 0), HH);
    int he = min(max(((p + 1) * rh + PP - 1) / PP + y1, 0), HH);
    int ws = min(max(q * rw / PP + x1, 0), WW);
    int we = min(max(((q + 1) * rw + PP - 1) / PP + x1, 0), WW);

    bool empty = (he <= hs) || (we <= ws);

    const float* fc = feat + c * (HH * WW);
    float m = -INFINITY;
    for (int h = hs; h < he; ++h) {
        const float* row = fc + h * WW;
        for (int w = ws; w < we; ++w)
            m = fmaxf(m, row[w]);
    }
    out[idx] = empty ? 0.0f : m;
}

extern "C" void kernel_launch(void* const* d_in, const int* in_sizes, int n_in,
                              void* d_out, int out_size, void* d_ws, size_t ws_size,
                              hipStream_t stream)
{
    const float* feat  = (const float*)d_in[0];
    const float* boxes = (const float*)d_in[1];
    // d_in[2] = output_size (7), d_in[3] = spatial_scale (1/16) — compiled in.
    float* out = (float*)d_out;

    int total = NBOX * CC * PP * PP;  // 6,422,528
    int block = 256;
    int grid  = (total + block - 1) / block;
    ROIPool_kernel<<<grid, block, 0, stream>>>(feat, boxes, out, total);
}

// Round 2
// 27.402 us; speedup vs baseline: 1.2417x; 1.2417x over previous
//
#include <hip/hip_runtime.h>

// ROI max-pool. feature_map: (1,256,50,50) f32, bboxes: (512,4) f32,
// out: (512,256,7,7) f32, scale = 1/16, pooled = 7.
//
// Strategy: transpose feature to NHWC in d_ws so channels are contiguous;
// then one block per box, wave-uniform bin loops with lanes over channels.

#define CC   256
#define HH   50
#define WW   50
#define NBOX 512
#define PP   7
#define SCL  (1.0f / 16.0f)
#define HW   (HH * WW)            // 2500
#define OUT_PER_BOX (CC * PP * PP) // 12544

// ---------- Kernel 1: (C, HW) -> (HW, C) transpose via 64x64 LDS tiles ----
__global__ __launch_bounds__(256) void transpose_kernel(
    const float* __restrict__ feat, float* __restrict__ featT)
{
    __shared__ float tile[64][65];          // +1 pad -> conflict-free column reads
    int tc = blockIdx.x & 3;                // channel tile 0..3
    int th = blockIdx.x >> 2;               // hw tile 0..39
    int c0 = tc * 64, h0 = th * 64;
    int lane = threadIdx.x & 63;
    int row4 = threadIdx.x >> 6;            // 0..3

    for (int it = 0; it < 16; ++it) {
        int r  = row4 + it * 4;             // c-row in tile
        int hw = h0 + lane;
        if (hw < HW)
            tile[r][lane] = feat[(c0 + r) * HW + hw];   // coalesced along hw
    }
    __syncthreads();
    for (int it = 0; it < 16; ++it) {
        int r  = row4 + it * 4;             // hw-row in tile
        int hw = h0 + r;
        if (hw < HW)
            featT[hw * CC + c0 + lane] = tile[lane][r]; // coalesced along c
    }
}

// ---------- Kernel 2: one block per box --------------------------------
__global__ __launch_bounds__(512) void pool_kernel(
    const float* __restrict__ featT,
    const float* __restrict__ boxes,
    float* __restrict__ out)
{
    __shared__ float res[OUT_PER_BOX];      // 50176 B: res[c*49 + pq]
    int n    = blockIdx.x;
    int tid  = threadIdx.x;
    int wave = tid >> 6;
    int lane = tid & 63;

    const float* b = boxes + n * 4;
    int x1 = (int)floorf(b[0] * SCL + 0.5f);
    int y1 = (int)floorf(b[1] * SCL + 0.5f);
    int x2 = (int)floorf(b[2] * SCL + 0.5f);
    int y2 = (int)floorf(b[3] * SCL + 0.5f);
    int rw = max(x2 - x1 + 1, 1);
    int rh = max(y2 - y1 + 1, 1);

    // wave w handles bins pq = w, w+8, ... : bounds are wave-uniform
    for (int pq = wave; pq < PP * PP; pq += 8) {
        int p = pq / PP, q = pq % PP;       // magic-mul, non-negative
        int hs = min(max(p * rh / PP + y1, 0), HH);
        int he = min(max(((p + 1) * rh + PP - 1) / PP + y1, 0), HH);
        int ws = min(max(q * rw / PP + x1, 0), WW);
        int we = min(max(((q + 1) * rw + PP - 1) / PP + x1, 0), WW);

        float m0 = -INFINITY, m1 = m0, m2 = m0, m3 = m0;
        for (int h = hs; h < he; ++h) {
            const float* base = featT + h * (WW * CC) + lane;
            for (int w = ws; w < we; ++w) {
                const float* pc = base + w * CC;   // lanes consecutive -> coalesced
                m0 = fmaxf(m0, pc[0]);
                m1 = fmaxf(m1, pc[64]);
                m2 = fmaxf(m2, pc[128]);
                m3 = fmaxf(m3, pc[192]);
            }
        }
        if ((he <= hs) || (we <= ws)) { m0 = m1 = m2 = m3 = 0.0f; }

        // store word = c*49+pq: lanes l and l+32 share a bank -> 2-way (free)
        res[(lane      ) * 49 + pq] = m0;
        res[(lane +  64) * 49 + pq] = m1;
        res[(lane + 128) * 49 + pq] = m2;
        res[(lane + 192) * 49 + pq] = m3;
    }
    __syncthreads();

    // fully-coalesced float4 writeback of the whole box (12544 f32)
    const float4* r4 = (const float4*)res;
    float4*       o4 = (float4*)(out + n * OUT_PER_BOX);
    for (int i = tid; i < OUT_PER_BOX / 4; i += 512)
        o4[i] = r4[i];
}

// ---------- Fallback (round-1 kernel) if ws too small -------------------
__global__ __launch_bounds__(256) void pool_direct_kernel(
    const float* __restrict__ feat,
    const float* __restrict__ boxes,
    float* __restrict__ out, int total)
{
    int idx = blockIdx.x * blockDim.x + threadIdx.x;
    if (idx >= total) return;
    int q = idx % PP;
    int t = idx / PP;
    int p = t % PP;
    t /= PP;
    int c = t & (CC - 1);
    int n = t >> 8;

    const float* b = boxes + n * 4;
    int x1 = (int)floorf(b[0] * SCL + 0.5f);
    int y1 = (int)floorf(b[1] * SCL + 0.5f);
    int x2 = (int)floorf(b[2] * SCL + 0.5f);
    int y2 = (int)floorf(b[3] * SCL + 0.5f);
    int rw = max(x2 - x1 + 1, 1);
    int rh = max(y2 - y1 + 1, 1);

    int hs = min(max(p * rh / PP + y1, 0), HH);
    int he = min(max(((p + 1) * rh + PP - 1) / PP + y1, 0), HH);
    int ws = min(max(q * rw / PP + x1, 0), WW);
    int we = min(max(((q + 1) * rw + PP - 1) / PP + x1, 0), WW);

    const float* fc = feat + c * HW;
    float m = -INFINITY;
    for (int h = hs; h < he; ++h)
        for (int w = ws; w < we; ++w)
            m = fmaxf(m, fc[h * WW + w]);
    out[idx] = ((he <= hs) || (we <= ws)) ? 0.0f : m;
}

extern "C" void kernel_launch(void* const* d_in, const int* in_sizes, int n_in,
                              void* d_out, int out_size, void* d_ws, size_t ws_size,
                              hipStream_t stream)
{
    const float* feat  = (const float*)d_in[0];
    const float* boxes = (const float*)d_in[1];
    float* out = (float*)d_out;

    const size_t needT = (size_t)HW * CC * sizeof(float);   // 2,560,000 B
    if (ws_size >= needT) {
        float* featT = (float*)d_ws;
        transpose_kernel<<<40 * 4, 256, 0, stream>>>(feat, featT);
        pool_kernel<<<NBOX, 512, 0, stream>>>(featT, boxes, out);
    } else {
        int total = NBOX * CC * PP * PP;
        pool_direct_kernel<<<(total + 255) / 256, 256, 0, stream>>>(
            feat, boxes, out, total);
    }
}